// Round 8
// baseline (194.852 us; speedup 1.0000x reference)
//
#include <hip/hip_runtime.h>
#include <hip/hip_bf16.h>
#include <math.h>

// B=2, S=2048, D=1024, H=16, HD=64. Inputs fp32, output fp32.
// R16: flash QBLK 64->128 with 8-wave (512-thread) blocks. Per-wave
// structure identical (16 q-rows/wave); K/V tile now shared by 8 waves ->
// staging bytes + LDS writes halve, barriers per q-row halve (one 8KB tile
// staged by TWO wave-level glds16 calls). Causal boundary = two diagonal
// tiles, mask generalized h<=w -> g=bb*4+h<=w (wave-uniform). Waves with
// zero valid keys in a tile skip the softmax update entirely (exact).
// gemm (R12 serial) and prep byte-identical to R15 (189.2us, passed).

#define Bdim  2
#define Sdim  2048
#define Ddim  1024
#define Hn    16
#define HDdim 64
#define Mdim  (Bdim * Sdim)   // 4096

// 0.125 (1/sqrt(64)) * log2(e): Q pre-scaled so QK^T is in log2 domain.
#define QSCALE 0.18033688011112042f

typedef unsigned short ushort_t;
typedef __attribute__((ext_vector_type(8))) short bfrag;   // 8 bf16 (4 VGPR)
typedef __attribute__((ext_vector_type(4))) float f4;

__device__ __forceinline__ ushort_t f2bf(float f) {
    union { float f; unsigned int i; } c;
    c.f = f;
    unsigned int x = c.i;
    unsigned int r = (x + 0x7fffu + ((x >> 16) & 1u)) >> 16;  // RNE
    return (ushort_t)r;
}

// packed bf16 convert: dst.lo = bf16(lo), dst.hi = bf16(hi)  [T12, m240]
__device__ __forceinline__ unsigned cvtpk(float lo, float hi) {
    unsigned r;
    asm("v_cvt_pk_bf16_f32 %0, %1, %2" : "=v"(r) : "v"(lo), "v"(hi));
    return r;
}

__device__ __forceinline__ void glds16(const void* g, void* l) {
    __builtin_amdgcn_global_load_lds(
        (const __attribute__((address_space(1))) unsigned int*)g,
        (__attribute__((address_space(3))) unsigned int*)l, 16, 0, 0);
}

// -------- prep: fused {cast x fp32->bf16} + {transpose-cast weights} -------
// grid (16,16,12): z<4 = wtrans quadrant z; z>=4 = cast_x slice (8x256 blk).
__global__ __launch_bounds__(256)
void prep(const float* __restrict__ x, ushort_t* __restrict__ xb,
          const float* __restrict__ W0, const float* __restrict__ W1,
          const float* __restrict__ W2, const float* __restrict__ W3,
          ushort_t* __restrict__ qkvT, ushort_t* __restrict__ oT)
{
    __shared__ ushort_t t[64][72];   // [n][k], padded (wtrans path only)
    const int tid = threadIdx.x;
    const int z = blockIdx.z;

    if (z >= 4) {
        // ---- cast_x: linear block over 2048 ----
        size_t blk = (size_t)(z - 4) * 256 + blockIdx.y * 16 + blockIdx.x;
        size_t i = (blk * 256 + tid) * 8;
        float4 a = *(const float4*)(x + i);
        float4 b = *(const float4*)(x + i + 4);
        ushort_t o[8] = {f2bf(a.x), f2bf(a.y), f2bf(a.z), f2bf(a.w),
                         f2bf(b.x), f2bf(b.y), f2bf(b.z), f2bf(b.w)};
        *(bfrag*)(xb + i) = *(const bfrag*)o;
        return;
    }

    // ---- wtrans: W[k][n] fp32 -> Wt[n][k] bf16 ----
    const float* W = (z == 0) ? W0 : (z == 1) ? W1 : (z == 2) ? W2 : W3;
    const int k0 = blockIdx.y * 64, n0 = blockIdx.x * 64;

    const int r = tid >> 4, c4 = (tid & 15) * 4;
    #pragma unroll
    for (int rr = 0; rr < 4; ++rr) {
        int k = r + rr * 16;
        float4 v = *(const float4*)&W[(size_t)(k0 + k) * Ddim + n0 + c4];
        t[c4 + 0][k] = f2bf(v.x);
        t[c4 + 1][k] = f2bf(v.y);
        t[c4 + 2][k] = f2bf(v.z);
        t[c4 + 3][k] = f2bf(v.w);
    }
    __syncthreads();
    ushort_t* out = (z < 3) ? (qkvT + (size_t)z * Ddim * Ddim) : oT;
    const int n = tid >> 2, kc = (tid & 3) * 16;
    *(bfrag*)&out[(size_t)(n0 + n) * Ddim + k0 + kc] = *(const bfrag*)&t[n][kc];
    *(bfrag*)&out[(size_t)(n0 + n) * Ddim + k0 + kc + 8] = *(const bfrag*)&t[n][kc + 8];
}

// ---------------- MFMA GEMM (m97 structure, NT; R12 serial K-loop) ---------
// MODE 0: Ntot=3072 fused QKV; scatter bf16 to Q,K [B,H,S,HD], Vt [B,H,HD,S].
//         Q is pre-scaled by QSCALE (softmax runs in exp2 domain).
// MODE 1: Ntot=1024; fp32 out [M,N].
template <int MODE>
__global__ __launch_bounds__(256)
void gemm_mfma(const ushort_t* __restrict__ A, const ushort_t* __restrict__ Bt,
               const float* __restrict__ bQ, const float* __restrict__ bK,
               const float* __restrict__ bV,
               ushort_t* __restrict__ oQ, ushort_t* __restrict__ oK,
               ushort_t* __restrict__ oVt, float* __restrict__ oF)
{
    __shared__ ushort_t As[128 * 32];   // [row][k], 64 B rows
    __shared__ ushort_t Bs[128 * 32];

    const int tid  = threadIdx.x;
    const int lane = tid & 63;
    const int w    = tid >> 6;
    const int l15  = lane & 15;
    const int quad = lane >> 4;
    const int wr   = w >> 1, wc = w & 1;
    const int m0 = blockIdx.y * 128;
    const int n0 = blockIdx.x * 128;

    f4 acc[4][4];
    #pragma unroll
    for (int i = 0; i < 4; ++i)
        #pragma unroll
        for (int j = 0; j < 4; ++j) acc[i][j] = (f4){0.f, 0.f, 0.f, 0.f};

    const int srow  = w * 32 + (lane >> 2);
    const int selem = (lane & 3) * 8;
    const ushort_t* gA = A  + (size_t)(m0 + srow) * Ddim + selem;
    const ushort_t* gB = Bt + (size_t)(n0 + srow) * Ddim + selem;
    char* lA0 = (char*)As + (w * 32) * 64;
    char* lB0 = (char*)Bs + (w * 32) * 64;

    for (int kk = 0; kk < Ddim; kk += 32) {
        __syncthreads();
        glds16(gA + kk,              lA0);
        glds16(gA + 16 * Ddim + kk,  lA0 + 1024);
        glds16(gB + kk,              lB0);
        glds16(gB + 16 * Ddim + kk,  lB0 + 1024);
        __syncthreads();

        bfrag Af[4], Bf[4];
        #pragma unroll
        for (int i = 0; i < 4; ++i)
            Af[i] = *(const bfrag*)&As[(wr * 64 + i * 16 + l15) * 32 + quad * 8];
        #pragma unroll
        for (int j = 0; j < 4; ++j)
            Bf[j] = *(const bfrag*)&Bs[(wc * 64 + j * 16 + l15) * 32 + quad * 8];
        #pragma unroll
        for (int i = 0; i < 4; ++i)
            #pragma unroll
            for (int j = 0; j < 4; ++j)
                acc[i][j] = __builtin_amdgcn_mfma_f32_16x16x32_bf16(Af[i], Bf[j], acc[i][j], 0, 0, 0);
    }

    if constexpr (MODE == 0) {
        const int sel   = n0 >> 10;
        const int dbase = n0 & 1023;
        const float* bias = (sel == 0) ? bQ : (sel == 1) ? bK : bV;
        ushort_t* dst = (sel == 0) ? oQ : (sel == 1) ? oK : oVt;
        #pragma unroll
        for (int j = 0; j < 4; ++j) {
            int dn = dbase + wc * 64 + j * 16 + l15;
            float bv = bias[dn];
            int h = dn >> 6, e = dn & 63;
            if (sel < 2) {
                // Q/K: [B,H,S,HD] scatter, per-element (row stride 128B)
                #pragma unroll
                for (int i = 0; i < 4; ++i) {
                    #pragma unroll
                    for (int r = 0; r < 4; ++r) {
                        int m = m0 + wr * 64 + i * 16 + quad * 4 + r;
                        int b = m >> 11, s = m & 2047;
                        float v = acc[i][j][r] + bv;
                        if (sel == 0) v *= QSCALE;
                        dst[((((size_t)b * Hn + h) * Sdim + s) << 6) + e] = f2bf(v);
                    }
                }
            } else {
                // Vt: [B,H,HD,S] — s consecutive across r -> paired stores
                #pragma unroll
                for (int i = 0; i < 4; ++i) {
                    #pragma unroll
                    for (int rp = 0; rp < 2; ++rp) {
                        int m = m0 + wr * 64 + i * 16 + quad * 4 + rp * 2;
                        int b = m >> 11, s = m & 2047;   // s even
                        unsigned pv = cvtpk(acc[i][j][rp * 2] + bv,
                                            acc[i][j][rp * 2 + 1] + bv);
                        *(unsigned*)&dst[(((size_t)b * Hn + h) * HDdim + e) * Sdim + s] = pv;
                    }
                }
            }
        }
    } else {
        #pragma unroll
        for (int j = 0; j < 4; ++j) {
            int n = n0 + wc * 64 + j * 16 + l15;
            float bv = bQ[n];   // bo
            #pragma unroll
            for (int i = 0; i < 4; ++i)
                #pragma unroll
                for (int r = 0; r < 4; ++r) {
                    int m = m0 + wr * 64 + i * 16 + quad * 4 + r;
                    oF[(size_t)m * Ddim + n] = acc[i][j][r] + bv;
                }
        }
    }
}

// ---------------- Flash attention: 8 waves / 128 q rows, async LDS dbuf ----
// Block = (qb, bh): 128 q rows, wave w owns rows qb*128 + 16w .. +15.
// 64-key tiles staged ONCE per block (2 glds16 of 8KB each), shared by all
// 8 waves. Main tiles fully valid; two diagonal tiles masked via
// g = bb*4+h vs w (wave-uniform). Zero-key waves skip the update (exact).
#define NBH (Bdim * Hn)       // 32

#define MFMA16(a, b, c) __builtin_amdgcn_mfma_f32_16x16x32_bf16(a, b, c, 0, 0, 0)
#define EXP2(x) __builtin_amdgcn_exp2f(x)

__global__ __launch_bounds__(512, 4)
void flash_mfma(const ushort_t* __restrict__ Q, const ushort_t* __restrict__ K,
                const ushort_t* __restrict__ Vt, ushort_t* __restrict__ ctx)
{
    __shared__ ushort_t KtS[2][64 * 64];   // [key][d], 16B blocks XOR-swizzled
    __shared__ ushort_t VsS[2][64 * 64];   // [d][key], same swizzle
    __shared__ ushort_t PTS[8][1024];      // per-wave P^T, fragment order

    const int tid  = threadIdx.x;
    const int lane = tid & 63;
    const int w    = tid >> 6;             // 0..7
    const int l15  = lane & 15;
    const int quad = lane >> 4;

    const int qb = 15 - (blockIdx.x >> 5);     // longest-first
    const int bh = blockIdx.x & 31;            // idx%8==bh%8 -> XCD affinity
    const int q0 = qb * 128;
    const int qw = q0 + w * 16;
    const int ntiles = 2 * qb + 2;             // 64-key tiles (last 2 masked)

    const ushort_t* Qrow = Q + ((size_t)bh * Sdim + qw + l15) * HDdim;
    const bfrag Qf0 = *(const bfrag*)(Qrow + quad * 8);
    const bfrag Qf1 = *(const bfrag*)(Qrow + 32 + quad * 8);

    const ushort_t* Kp = K  + (size_t)bh * Sdim * HDdim;
    const ushort_t* Vp = Vt + (size_t)bh * HDdim * Sdim;

    // --- staging: pre-swizzled global source -> linear LDS dest ---
    // 512 threads x 16B = one full 8KB tile per glds16 call.
    // thread writes LDS 16B block (row = tid>>3, cb = tid&7);
    // content = global col block cb ^ (row&7)   (row&7 == (tid>>3)&7).
    const int srow = tid >> 3;                               // 0..63
    const int scol = ((tid & 7) ^ ((tid >> 3) & 7)) * 8;     // swizzled elems
    const ushort_t* gK = Kp + (size_t)srow * HDdim + scol;
    const ushort_t* gV = Vp + (size_t)srow * Sdim + scol;
    char* ldsK = (char*)KtS + w * 1024;                      // wave-uniform
    char* ldsV = (char*)VsS + w * 1024;
    ushort_t* PTw = PTS[w];

    // --- fragment-read swizzled column offsets (row&7 == l15&7) ---
    const int sw = l15 & 7;
    const int c0 = (quad ^ sw) << 4;    // bytes, k-half 0
    const int c1 = c0 ^ 64;             // k-half 1 (block quad^4)
    const char* KtR = (const char*)KtS + l15 * 128;
    const char* VsR = (const char*)VsS + l15 * 128;

    f4 O[4];
    #pragma unroll
    for (int c = 0; c < 4; ++c) O[c] = (f4){0.f, 0.f, 0.f, 0.f};
    float m_prev = -INFINITY, l_run = 0.f;

    // prologue: stage tile 0 -> buf 0 (2 calls: K tile + V tile)
    glds16(gK, ldsK);
    glds16(gV, ldsV);
    __syncthreads();

    for (int kt = 0; kt < ntiles - 1; ++kt) {
        const int k0  = kt << 6;
        const int buf = kt & 1;
        const int nb  = buf ^ 1;

        // STAGE next tile into other buffer; latency hidden by this tile's
        // compute; drained by the __syncthreads at the end of this iter.
        {
            const size_t kn = (size_t)(k0 + 64);
            glds16(gK + kn * HDdim, ldsK + nb * 8192);
            glds16(gV + kn,         ldsV + nb * 8192);
        }

        const char* Kb = KtR + buf * 8192;
        const char* Vb = VsR + buf * 8192;

        if (kt < 2 * qb) {
            // ---- fully-valid tile ----
            float p[4][4];
            #pragma unroll
            for (int h = 0; h < 4; ++h) {
                bfrag a0 = *(const bfrag*)(Kb + h * 2048 + c0);
                bfrag a1 = *(const bfrag*)(Kb + h * 2048 + c1);
                f4 s = (f4){0.f, 0.f, 0.f, 0.f};
                s = MFMA16(a0, Qf0, s);
                s = MFMA16(a1, Qf1, s);
                #pragma unroll
                for (int r = 0; r < 4; ++r) p[h][r] = s[r];
            }

            float mh0 = fmaxf(fmaxf(p[0][0], p[0][1]), fmaxf(p[0][2], p[0][3]));
            float mh1 = fmaxf(fmaxf(p[1][0], p[1][1]), fmaxf(p[1][2], p[1][3]));
            float mh2 = fmaxf(fmaxf(p[2][0], p[2][1]), fmaxf(p[2][2], p[2][3]));
            float mh3 = fmaxf(fmaxf(p[3][0], p[3][1]), fmaxf(p[3][2], p[3][3]));
            float mt = fmaxf(fmaxf(mh0, mh1), fmaxf(mh2, mh3));
            mt = fmaxf(mt, __shfl_xor(mt, 16, 64));
            mt = fmaxf(mt, __shfl_xor(mt, 32, 64));

            if (__any(mt > m_prev + 8.f)) {     // defer-max rescale
                float m_new = fmaxf(m_prev, mt);
                float alpha = EXP2(m_prev - m_new);
                l_run *= alpha;
                #pragma unroll
                for (int r = 0; r < 4; ++r) {
                    float ar = __shfl(alpha, (lane & 48) + quad * 4 + r, 64);
                    #pragma unroll
                    for (int c = 0; c < 4; ++c) O[c][r] *= ar;
                }
                m_prev = m_new;
            }

            float rs0 = 0.f, rs1 = 0.f, rs2 = 0.f, rs3 = 0.f;
            #pragma unroll
            for (int r = 0; r < 4; ++r) {
                p[0][r] = EXP2(p[0][r] - m_prev); rs0 += p[0][r];
                p[1][r] = EXP2(p[1][r] - m_prev); rs1 += p[1][r];
                p[2][r] = EXP2(p[2][r] - m_prev); rs2 += p[2][r];
                p[3][r] = EXP2(p[3][r] - m_prev); rs3 += p[3][r];
            }
            float rsum = (rs0 + rs1) + (rs2 + rs3);
            rsum += __shfl_xor(rsum, 16, 64);
            rsum += __shfl_xor(rsum, 32, 64);
            l_run += rsum;

            #pragma unroll
            for (int h = 0; h < 4; ++h) {
                uint2 pw;
                pw.x = cvtpk(p[h][0], p[h][1]);
                pw.y = cvtpk(p[h][2], p[h][3]);
                *(uint2*)&PTw[((((h << 1) + (quad >> 1)) * 16 + l15) << 3) + (quad & 1) * 4] = pw;
            }
            bfrag pA0 = *(const bfrag*)&PTw[lane * 8];
            bfrag pA1 = *(const bfrag*)&PTw[512 + lane * 8];

            #pragma unroll
            for (int c = 0; c < 4; ++c) {
                bfrag v0 = *(const bfrag*)(Vb + c * 2048 + c0);
                bfrag v1 = *(const bfrag*)(Vb + c * 2048 + c1);
                O[c] = MFMA16(pA0, v0, O[c]);
                O[c] = MFMA16(pA1, v1, O[c]);
            }
        } else {
            // ---- diagonal tile 1 (bb=0): key blocks g = h vs wave w ----
            float p[4][4];
            float mt = -INFINITY;
            #pragma unroll
            for (int h = 0; h < 4; ++h) {
                if (h <= w) {                       // wave-uniform branch
                    bfrag a0 = *(const bfrag*)(Kb + h * 2048 + c0);
                    bfrag a1 = *(const bfrag*)(Kb + h * 2048 + c1);
                    f4 s = (f4){0.f, 0.f, 0.f, 0.f};
                    s = MFMA16(a0, Qf0, s);
                    s = MFMA16(a1, Qf1, s);
                    if (h == w) {
                        #pragma unroll
                        for (int r = 0; r < 4; ++r) {
                            float v = (quad * 4 + r <= l15) ? s[r] : -INFINITY;
                            p[h][r] = v;
                            mt = fmaxf(mt, v);
                        }
                    } else {
                        #pragma unroll
                        for (int r = 0; r < 4; ++r) {
                            p[h][r] = s[r];
                            mt = fmaxf(mt, s[r]);
                        }
                    }
                } else {
                    #pragma unroll
                    for (int r = 0; r < 4; ++r) p[h][r] = -INFINITY;
                }
            }
            mt = fmaxf(mt, __shfl_xor(mt, 16, 64));
            mt = fmaxf(mt, __shfl_xor(mt, 32, 64));

            if (__any(mt > m_prev + 8.f)) {
                float m_new = fmaxf(m_prev, mt);
                float alpha = EXP2(m_prev - m_new);
                l_run *= alpha;
                #pragma unroll
                for (int r = 0; r < 4; ++r) {
                    float ar = __shfl(alpha, (lane & 48) + quad * 4 + r, 64);
                    #pragma unroll
                    for (int c = 0; c < 4; ++c) O[c][r] *= ar;
                }
                m_prev = m_new;
            }

            float rsum = 0.f;
            #pragma unroll
            for (int h = 0; h < 4; ++h)
                #pragma unroll
                for (int r = 0; r < 4; ++r) {
                    float e = EXP2(p[h][r] - m_prev);   // exp2(-inf)=0
                    p[h][r] = e;
                    rsum += e;
                }
            rsum += __shfl_xor(rsum, 16, 64);
            rsum += __shfl_xor(rsum, 32, 64);
            l_run += rsum;

            #pragma unroll
            for (int h = 0; h < 4; ++h) {
                uint2 pw;
                pw.x = cvtpk(p[h][0], p[h][1]);
                pw.y = cvtpk(p[h][2], p[h][3]);
                *(uint2*)&PTw[((((h << 1) + (quad >> 1)) * 16 + l15) << 3) + (quad & 1) * 4] = pw;
            }
            bfrag pA0 = *(const bfrag*)&PTw[lane * 8];
            #pragma unroll
            for (int c = 0; c < 4; ++c) {
                bfrag v0 = *(const bfrag*)(Vb + c * 2048 + c0);
                O[c] = MFMA16(pA0, v0, O[c]);
            }
            if (w >= 2) {                           // keys 32..63 need w>=2
                bfrag pA1 = *(const bfrag*)&PTw[512 + lane * 8];
                #pragma unroll
                for (int c = 0; c < 4; ++c) {
                    bfrag v1 = *(const bfrag*)(Vb + c * 2048 + c1);
                    O[c] = MFMA16(pA1, v1, O[c]);
                }
            }
        }

        __syncthreads();   // next tile landed (all waves); buf reusable
    }

    // ---- diagonal tile 2 (bb=1): key blocks g = 4+h vs wave w ----
    if (w >= 4) {      // waves 0..3 have zero valid keys here (exact skip)
        const int buf = (ntiles - 1) & 1;
        const char* Kb = KtR + buf * 8192;
        const char* Vb = VsR + buf * 8192;

        float p[4][4];
        float mt = -INFINITY;
        #pragma unroll
        for (int h = 0; h < 4; ++h) {
            const int g = 4 + h;
            if (g <= w) {                       // wave-uniform branch
                bfrag a0 = *(const bfrag*)(Kb + h * 2048 + c0);
                bfrag a1 = *(const bfrag*)(Kb + h * 2048 + c1);
                f4 s = (f4){0.f, 0.f, 0.f, 0.f};
                s = MFMA16(a0, Qf0, s);
                s = MFMA16(a1, Qf1, s);
                if (g == w) {
                    #pragma unroll
                    for (int r = 0; r < 4; ++r) {
                        float v = (quad * 4 + r <= l15) ? s[r] : -INFINITY;
                        p[h][r] = v;
                        mt = fmaxf(mt, v);
                    }
                } else {
                    #pragma unroll
                    for (int r = 0; r < 4; ++r) {
                        p[h][r] = s[r];
                        mt = fmaxf(mt, s[r]);
                    }
                }
            } else {
                #pragma unroll
                for (int r = 0; r < 4; ++r) p[h][r] = -INFINITY;
            }
        }
        mt = fmaxf(mt, __shfl_xor(mt, 16, 64));
        mt = fmaxf(mt, __shfl_xor(mt, 32, 64));

        if (__any(mt > m_prev + 8.f)) {
            float m_new = fmaxf(m_prev, mt);
            float alpha = EXP2(m_prev - m_new);
            l_run *= alpha;
            #pragma unroll
            for (int r = 0; r < 4; ++r) {
                float ar = __shfl(alpha, (lane & 48) + quad * 4 + r, 64);
                #pragma unroll
                for (int c = 0; c < 4; ++c) O[c][r] *= ar;
            }
            m_prev = m_new;
        }

        float rsum = 0.f;
        #pragma unroll
        for (int h = 0; h < 4; ++h)
            #pragma unroll
            for (int r = 0; r < 4; ++r) {
                float e = EXP2(p[h][r] - m_prev);   // exp2(-inf)=0 for masked
                p[h][r] = e;
                rsum += e;
            }
        rsum += __shfl_xor(rsum, 16, 64);
        rsum += __shfl_xor(rsum, 32, 64);
        l_run += rsum;

        #pragma unroll
        for (int h = 0; h < 4; ++h) {
            uint2 pw;
            pw.x = cvtpk(p[h][0], p[h][1]);
            pw.y = cvtpk(p[h][2], p[h][3]);
            *(uint2*)&PTw[((((h << 1) + (quad >> 1)) * 16 + l15) << 3) + (quad & 1) * 4] = pw;
        }
        bfrag pA0 = *(const bfrag*)&PTw[lane * 8];
        #pragma unroll
        for (int c = 0; c < 4; ++c) {
            bfrag v0 = *(const bfrag*)(Vb + c * 2048 + c0);
            O[c] = MFMA16(pA0, v0, O[c]);
        }
        if (w >= 6) {                           // keys 96..127 need w>=6
            bfrag pA1 = *(const bfrag*)&PTw[512 + lane * 8];
            #pragma unroll
            for (int c = 0; c < 4; ++c) {
                bfrag v1 = *(const bfrag*)(Vb + c * 2048 + c1);
                O[c] = MFMA16(pA1, v1, O[c]);
            }
        }
    }

    // epilogue: bf16 ctx [B,S,D]
    const int b = bh >> 4, h = bh & 15;
    #pragma unroll
    for (int r = 0; r < 4; ++r) {
        float inv_l = 1.0f / __shfl(l_run, (lane & 48) + quad * 4 + r, 64);
        size_t base = ((size_t)b * Sdim + qw + quad * 4 + r) * Ddim + h * HDdim + l15;
        #pragma unroll
        for (int c = 0; c < 4; ++c)
            ctx[base + c * 16] = f2bf(O[c][r] * inv_l);
    }
}

// ---------------- launch ----------------
extern "C" void kernel_launch(void* const* d_in, const int* in_sizes, int n_in,
                              void* d_out, int out_size, void* d_ws, size_t ws_size,
                              hipStream_t stream)
{
    const int NX = Mdim * Ddim;
    const int NW = Ddim * Ddim;
    int xi = 0, wi[4] = {1, 3, 5, 7}, bi[4] = {2, 4, 6, 8}, nw = 0, nb = 0;
    bool sized = true;
    for (int i = 0; i < 9; ++i) {
        if (in_sizes[i] == NX) xi = i;
        else if (in_sizes[i] == NW) { if (nw < 4) wi[nw++] = i; }
        else if (in_sizes[i] == Ddim) { if (nb < 4) bi[nb++] = i; }
        else sized = false;
    }
    int iWq, iWk, iWv, iWo, ibq, ibk, ibv, ibo;
    if (!sized || xi == 0) {
        xi = 0; iWq = 1; ibq = 2; iWk = 3; ibk = 4; iWv = 5; ibv = 6; iWo = 7; ibo = 8;
    } else {
        iWk = wi[0]; iWo = wi[1]; iWq = wi[2]; iWv = wi[3];
        ibk = bi[0]; ibo = bi[1]; ibq = bi[2]; ibv = bi[3];
    }

    const float* x  = (const float*)d_in[xi];
    const float* Wq = (const float*)d_in[iWq];
    const float* bq = (const float*)d_in[ibq];
    const float* Wk = (const float*)d_in[iWk];
    const float* bk = (const float*)d_in[ibk];
    const float* Wv = (const float*)d_in[iWv];
    const float* bv = (const float*)d_in[ibv];
    const float* Wo = (const float*)d_in[iWo];
    const float* bo = (const float*)d_in[ibo];
    float* out = (float*)d_out;

    const size_t elems = (size_t)Mdim * Ddim;
    const size_t welems = (size_t)Ddim * Ddim;
    ushort_t* Qb    = (ushort_t*)d_ws;
    ushort_t* Kb    = Qb + elems;
    ushort_t* Vtb   = Kb + elems;
    ushort_t* Cb    = Vtb + elems;
    ushort_t* xb    = Cb + elems;
    ushort_t* qkvT  = xb + elems;
    ushort_t* WoT   = qkvT + 3 * welems;

    dim3 blk(256);
    // fused prep: z<4 wtrans quadrants, z>=4 cast_x slices (8*256 = 2048 blk)
    prep<<<dim3(16, 16, 12), blk, 0, stream>>>(x, xb, Wq, Wk, Wv, Wo, qkvT, WoT);

    gemm_mfma<0><<<dim3(3 * Ddim / 128, Mdim / 128), blk, 0, stream>>>(
        xb, qkvT, bq, bk, bv, Qb, Kb, Vtb, nullptr);

    // 512-thread blocks: idx = (15-qb)*32 + bh  (idx%8==bh%8 -> XCD locality)
    flash_mfma<<<dim3(16 * NBH), dim3(512), 0, stream>>>(Qb, Kb, Vtb, Cb);

    gemm_mfma<1><<<dim3(Ddim / 128, Mdim / 128), blk, 0, stream>>>(
        Cb, WoT, bo, nullptr, nullptr, nullptr, nullptr, nullptr, out);
}

// Round 9
// 193.096 us; speedup vs baseline: 1.0091x; 1.0091x over previous
//
#include <hip/hip_runtime.h>
#include <hip/hip_bf16.h>
#include <math.h>

// B=2, S=2048, D=1024, H=16, HD=64. Inputs fp32, output fp32.
// R17: flash reverted to R15 exactly (44.6us best; R16's 8-wave blocks
// regressed to 51.2 -> barrier frequency was not the lever). GEMM keeps
// R12's proven serial fence shape but batches TWO K-steps per barrier
// pair (stage kk & kk+32 -> 2 bufs, one drain, 32 MFMAs): barrier
// instances halve, two load latencies collapse into one drain. Plus
// bijective XCD swizzle (T1) on both GEMM grids for L2 A-panel reuse.

#define Bdim  2
#define Sdim  2048
#define Ddim  1024
#define Hn    16
#define HDdim 64
#define Mdim  (Bdim * Sdim)   // 4096

// 0.125 (1/sqrt(64)) * log2(e): Q pre-scaled so QK^T is in log2 domain.
#define QSCALE 0.18033688011112042f

typedef unsigned short ushort_t;
typedef __attribute__((ext_vector_type(8))) short bfrag;   // 8 bf16 (4 VGPR)
typedef __attribute__((ext_vector_type(4))) float f4;

__device__ __forceinline__ ushort_t f2bf(float f) {
    union { float f; unsigned int i; } c;
    c.f = f;
    unsigned int x = c.i;
    unsigned int r = (x + 0x7fffu + ((x >> 16) & 1u)) >> 16;  // RNE
    return (ushort_t)r;
}

// packed bf16 convert: dst.lo = bf16(lo), dst.hi = bf16(hi)  [T12, m240]
__device__ __forceinline__ unsigned cvtpk(float lo, float hi) {
    unsigned r;
    asm("v_cvt_pk_bf16_f32 %0, %1, %2" : "=v"(r) : "v"(lo), "v"(hi));
    return r;
}

__device__ __forceinline__ void glds16(const void* g, void* l) {
    __builtin_amdgcn_global_load_lds(
        (const __attribute__((address_space(1))) unsigned int*)g,
        (__attribute__((address_space(3))) unsigned int*)l, 16, 0, 0);
}

// -------- prep: fused {cast x fp32->bf16} + {transpose-cast weights} -------
// grid (16,16,12): z<4 = wtrans quadrant z; z>=4 = cast_x slice (8x256 blk).
__global__ __launch_bounds__(256)
void prep(const float* __restrict__ x, ushort_t* __restrict__ xb,
          const float* __restrict__ W0, const float* __restrict__ W1,
          const float* __restrict__ W2, const float* __restrict__ W3,
          ushort_t* __restrict__ qkvT, ushort_t* __restrict__ oT)
{
    __shared__ ushort_t t[64][72];   // [n][k], padded (wtrans path only)
    const int tid = threadIdx.x;
    const int z = blockIdx.z;

    if (z >= 4) {
        // ---- cast_x: linear block over 2048 ----
        size_t blk = (size_t)(z - 4) * 256 + blockIdx.y * 16 + blockIdx.x;
        size_t i = (blk * 256 + tid) * 8;
        float4 a = *(const float4*)(x + i);
        float4 b = *(const float4*)(x + i + 4);
        ushort_t o[8] = {f2bf(a.x), f2bf(a.y), f2bf(a.z), f2bf(a.w),
                         f2bf(b.x), f2bf(b.y), f2bf(b.z), f2bf(b.w)};
        *(bfrag*)(xb + i) = *(const bfrag*)o;
        return;
    }

    // ---- wtrans: W[k][n] fp32 -> Wt[n][k] bf16 ----
    const float* W = (z == 0) ? W0 : (z == 1) ? W1 : (z == 2) ? W2 : W3;
    const int k0 = blockIdx.y * 64, n0 = blockIdx.x * 64;

    const int r = tid >> 4, c4 = (tid & 15) * 4;
    #pragma unroll
    for (int rr = 0; rr < 4; ++rr) {
        int k = r + rr * 16;
        float4 v = *(const float4*)&W[(size_t)(k0 + k) * Ddim + n0 + c4];
        t[c4 + 0][k] = f2bf(v.x);
        t[c4 + 1][k] = f2bf(v.y);
        t[c4 + 2][k] = f2bf(v.z);
        t[c4 + 3][k] = f2bf(v.w);
    }
    __syncthreads();
    ushort_t* out = (z < 3) ? (qkvT + (size_t)z * Ddim * Ddim) : oT;
    const int n = tid >> 2, kc = (tid & 3) * 16;
    *(bfrag*)&out[(size_t)(n0 + n) * Ddim + k0 + kc] = *(const bfrag*)&t[n][kc];
    *(bfrag*)&out[(size_t)(n0 + n) * Ddim + k0 + kc + 8] = *(const bfrag*)&t[n][kc + 8];
}

// ---------------- MFMA GEMM (m97 structure; 2-step-batched barriers) -------
// MODE 0: Ntot=3072 fused QKV; scatter bf16 to Q,K [B,H,S,HD], Vt [B,H,HD,S].
//         Q is pre-scaled by QSCALE (softmax runs in exp2 domain).
// MODE 1: Ntot=1024; fp32 out [M,N].
// K-loop: per iteration stage kk AND kk+32 into two buffers (8 glds16 in
// flight), one drain barrier, compute 32 MFMAs. Same fence semantics as
// R12's proven serial loop, half the barrier instances.
// Block index XCD-swizzled (nwg % 8 == 0 -> simple bijective form).
template <int MODE>
__global__ __launch_bounds__(256)
void gemm_mfma(const ushort_t* __restrict__ A, const ushort_t* __restrict__ Bt,
               const float* __restrict__ bQ, const float* __restrict__ bK,
               const float* __restrict__ bV,
               ushort_t* __restrict__ oQ, ushort_t* __restrict__ oK,
               ushort_t* __restrict__ oVt, float* __restrict__ oF)
{
    __shared__ ushort_t As[2][128 * 32];   // [buf][row][k], 64 B rows
    __shared__ ushort_t Bs[2][128 * 32];

    const int tid  = threadIdx.x;
    const int lane = tid & 63;
    const int w    = tid >> 6;
    const int l15  = lane & 15;
    const int quad = lane >> 4;
    const int wr   = w >> 1, wc = w & 1;

    // XCD-aware bijective swizzle: consecutive tiles land on one XCD
    const int nbx = gridDim.x;
    int bid = blockIdx.y * nbx + blockIdx.x;
    const int chunk = (nbx * gridDim.y) >> 3;   // nwg/8 (nwg%8==0)
    bid = (bid & 7) * chunk + (bid >> 3);
    const int m0 = (bid / nbx) * 128;
    const int n0 = (bid % nbx) * 128;

    f4 acc[4][4];
    #pragma unroll
    for (int i = 0; i < 4; ++i)
        #pragma unroll
        for (int j = 0; j < 4; ++j) acc[i][j] = (f4){0.f, 0.f, 0.f, 0.f};

    const int srow  = w * 32 + (lane >> 2);
    const int selem = (lane & 3) * 8;
    const ushort_t* gA = A  + (size_t)(m0 + srow) * Ddim + selem;
    const ushort_t* gB = Bt + (size_t)(n0 + srow) * Ddim + selem;
    char* lA0 = (char*)As + (w * 32) * 64;     // wave-uniform dest (buf 0)
    char* lB0 = (char*)Bs + (w * 32) * 64;

    for (int kk = 0; kk < Ddim; kk += 64) {
        __syncthreads();   // all waves done reading both bufs
        glds16(gA + kk,                   lA0);
        glds16(gA + 16 * Ddim + kk,       lA0 + 1024);
        glds16(gB + kk,                   lB0);
        glds16(gB + 16 * Ddim + kk,       lB0 + 1024);
        glds16(gA + kk + 32,              lA0 + 8192);
        glds16(gA + 16 * Ddim + kk + 32,  lA0 + 8192 + 1024);
        glds16(gB + kk + 32,              lB0 + 8192);
        glds16(gB + 16 * Ddim + kk + 32,  lB0 + 8192 + 1024);
        __syncthreads();   // both halves landed for all waves

        #pragma unroll
        for (int half = 0; half < 2; ++half) {
            bfrag Af[4], Bf[4];
            #pragma unroll
            for (int i = 0; i < 4; ++i)
                Af[i] = *(const bfrag*)&As[half][(wr * 64 + i * 16 + l15) * 32 + quad * 8];
            #pragma unroll
            for (int j = 0; j < 4; ++j)
                Bf[j] = *(const bfrag*)&Bs[half][(wc * 64 + j * 16 + l15) * 32 + quad * 8];
            #pragma unroll
            for (int i = 0; i < 4; ++i)
                #pragma unroll
                for (int j = 0; j < 4; ++j)
                    acc[i][j] = __builtin_amdgcn_mfma_f32_16x16x32_bf16(Af[i], Bf[j], acc[i][j], 0, 0, 0);
        }
    }

    if constexpr (MODE == 0) {
        const int sel   = n0 >> 10;
        const int dbase = n0 & 1023;
        const float* bias = (sel == 0) ? bQ : (sel == 1) ? bK : bV;
        ushort_t* dst = (sel == 0) ? oQ : (sel == 1) ? oK : oVt;
        #pragma unroll
        for (int j = 0; j < 4; ++j) {
            int dn = dbase + wc * 64 + j * 16 + l15;
            float bv = bias[dn];
            int h = dn >> 6, e = dn & 63;
            if (sel < 2) {
                // Q/K: [B,H,S,HD] scatter, per-element (row stride 128B)
                #pragma unroll
                for (int i = 0; i < 4; ++i) {
                    #pragma unroll
                    for (int r = 0; r < 4; ++r) {
                        int m = m0 + wr * 64 + i * 16 + quad * 4 + r;
                        int b = m >> 11, s = m & 2047;
                        float v = acc[i][j][r] + bv;
                        if (sel == 0) v *= QSCALE;
                        dst[((((size_t)b * Hn + h) * Sdim + s) << 6) + e] = f2bf(v);
                    }
                }
            } else {
                // Vt: [B,H,HD,S] — s consecutive across r -> paired stores
                #pragma unroll
                for (int i = 0; i < 4; ++i) {
                    #pragma unroll
                    for (int rp = 0; rp < 2; ++rp) {
                        int m = m0 + wr * 64 + i * 16 + quad * 4 + rp * 2;
                        int b = m >> 11, s = m & 2047;   // s even
                        unsigned pv = cvtpk(acc[i][j][rp * 2] + bv,
                                            acc[i][j][rp * 2 + 1] + bv);
                        *(unsigned*)&dst[(((size_t)b * Hn + h) * HDdim + e) * Sdim + s] = pv;
                    }
                }
            }
        }
    } else {
        #pragma unroll
        for (int j = 0; j < 4; ++j) {
            int n = n0 + wc * 64 + j * 16 + l15;
            float bv = bQ[n];   // bo
            #pragma unroll
            for (int i = 0; i < 4; ++i)
                #pragma unroll
                for (int r = 0; r < 4; ++r) {
                    int m = m0 + wr * 64 + i * 16 + quad * 4 + r;
                    oF[(size_t)m * Ddim + n] = acc[i][j][r] + bv;
                }
        }
    }
}

// ---------------- Flash attention: 4 waves / 64 q rows, async LDS dbuf -----
// (byte-identical to R15, which passed at 44.6us)
#define NBH (Bdim * Hn)       // 32

#define MFMA16(a, b, c) __builtin_amdgcn_mfma_f32_16x16x32_bf16(a, b, c, 0, 0, 0)
#define EXP2(x) __builtin_amdgcn_exp2f(x)

__global__ __launch_bounds__(256, 4)
void flash_mfma(const ushort_t* __restrict__ Q, const ushort_t* __restrict__ K,
                const ushort_t* __restrict__ Vt, ushort_t* __restrict__ ctx)
{
    __shared__ ushort_t KtS[2][64 * 64];   // [key][d], 16B blocks XOR-swizzled
    __shared__ ushort_t VsS[2][64 * 64];   // [d][key], same swizzle
    __shared__ ushort_t PTS[4][1024];      // per-wave P^T, fragment order

    const int tid  = threadIdx.x;
    const int lane = tid & 63;
    const int w    = tid >> 6;
    const int l15  = lane & 15;
    const int quad = lane >> 4;

    const int qb = 31 - (blockIdx.x >> 5);     // longest-first
    const int bh = blockIdx.x & 31;            // idx%8==bh%8 -> XCD affinity
    const int q0 = qb * 64;
    const int qw = q0 + w * 16;
    const int ntiles = qb + 1;                 // 64-key tiles (last is masked)

    const ushort_t* Qrow = Q + ((size_t)bh * Sdim + qw + l15) * HDdim;
    const bfrag Qf0 = *(const bfrag*)(Qrow + quad * 8);
    const bfrag Qf1 = *(const bfrag*)(Qrow + 32 + quad * 8);

    const ushort_t* Kp = K  + (size_t)bh * Sdim * HDdim;
    const ushort_t* Vp = Vt + (size_t)bh * HDdim * Sdim;

    // --- staging: pre-swizzled global source -> linear LDS dest ---
    const int srow = w * 8 + (lane >> 3);                    // 0..31 (+32 half 2)
    const int scol = ((lane & 7) ^ (lane >> 3)) * 8;         // swizzled elems
    const ushort_t* gK = Kp + (size_t)srow * HDdim + scol;
    const ushort_t* gV = Vp + (size_t)srow * Sdim + scol;
    char* ldsK = (char*)KtS + w * 1024;                      // wave-uniform
    char* ldsV = (char*)VsS + w * 1024;
    ushort_t* PTw = PTS[w];

    // --- fragment-read swizzled column offsets (row&7 == l15&7) ---
    const int sw = l15 & 7;
    const int c0 = (quad ^ sw) << 4;    // bytes, k-half 0
    const int c1 = c0 ^ 64;             // k-half 1 (block quad^4)
    const char* KtR = (const char*)KtS + l15 * 128;
    const char* VsR = (const char*)VsS + l15 * 128;

    f4 O[4];
    #pragma unroll
    for (int c = 0; c < 4; ++c) O[c] = (f4){0.f, 0.f, 0.f, 0.f};
    float m_prev = -INFINITY, l_run = 0.f;

    // prologue: stage tile 0 -> buf 0
    glds16(gK,                       ldsK);
    glds16(gK + 32 * HDdim,          ldsK + 4096);
    glds16(gV,                       ldsV);
    glds16(gV + (size_t)32 * Sdim,   ldsV + 4096);
    __syncthreads();

    for (int kt = 0; kt < ntiles - 1; ++kt) {
        const int k0  = kt << 6;
        const int buf = kt & 1;
        const int nb  = buf ^ 1;

        // STAGE next tile into other buffer; latency hidden by this tile's
        // compute; drained by the __syncthreads at the end of this iter.
        {
            const size_t kn = (size_t)(k0 + 64);
            glds16(gK + kn * HDdim,               ldsK + nb * 8192);
            glds16(gK + (kn + 32) * HDdim,        ldsK + nb * 8192 + 4096);
            glds16(gV + kn,                       ldsV + nb * 8192);
            glds16(gV + kn + (size_t)32 * Sdim,   ldsV + nb * 8192 + 4096);
        }

        const char* Kb = KtR + buf * 8192;
        const char* Vb = VsR + buf * 8192;

        // QK^T (log2 domain): p[h][r] = score(key k0+h*16+quad*4+r, q qw+l15)
        float p[4][4];
        #pragma unroll
        for (int h = 0; h < 4; ++h) {
            bfrag a0 = *(const bfrag*)(Kb + h * 2048 + c0);
            bfrag a1 = *(const bfrag*)(Kb + h * 2048 + c1);
            f4 s = (f4){0.f, 0.f, 0.f, 0.f};
            s = MFMA16(a0, Qf0, s);
            s = MFMA16(a1, Qf1, s);
            #pragma unroll
            for (int r = 0; r < 4; ++r) p[h][r] = s[r];
        }

        float mh0 = fmaxf(fmaxf(p[0][0], p[0][1]), fmaxf(p[0][2], p[0][3]));
        float mh1 = fmaxf(fmaxf(p[1][0], p[1][1]), fmaxf(p[1][2], p[1][3]));
        float mh2 = fmaxf(fmaxf(p[2][0], p[2][1]), fmaxf(p[2][2], p[2][3]));
        float mh3 = fmaxf(fmaxf(p[3][0], p[3][1]), fmaxf(p[3][2], p[3][3]));
        float mt = fmaxf(fmaxf(mh0, mh1), fmaxf(mh2, mh3));
        mt = fmaxf(mt, __shfl_xor(mt, 16, 64));
        mt = fmaxf(mt, __shfl_xor(mt, 32, 64));

        if (__any(mt > m_prev + 8.f)) {     // defer-max rescale
            float m_new = fmaxf(m_prev, mt);
            float alpha = EXP2(m_prev - m_new);
            l_run *= alpha;
            #pragma unroll
            for (int r = 0; r < 4; ++r) {
                float ar = __shfl(alpha, (lane & 48) + quad * 4 + r, 64);
                #pragma unroll
                for (int c = 0; c < 4; ++c) O[c][r] *= ar;
            }
            m_prev = m_new;
        }

        float rs0 = 0.f, rs1 = 0.f, rs2 = 0.f, rs3 = 0.f;
        #pragma unroll
        for (int r = 0; r < 4; ++r) {
            p[0][r] = EXP2(p[0][r] - m_prev); rs0 += p[0][r];
            p[1][r] = EXP2(p[1][r] - m_prev); rs1 += p[1][r];
            p[2][r] = EXP2(p[2][r] - m_prev); rs2 += p[2][r];
            p[3][r] = EXP2(p[3][r] - m_prev); rs3 += p[3][r];
        }
        float rsum = (rs0 + rs1) + (rs2 + rs3);
        rsum += __shfl_xor(rsum, 16, 64);
        rsum += __shfl_xor(rsum, 32, 64);
        l_run += rsum;

        // P^T -> per-wave LDS, fragment order [keyblk][q][8]; packed cvt_pk
        #pragma unroll
        for (int h = 0; h < 4; ++h) {
            uint2 pw;
            pw.x = cvtpk(p[h][0], p[h][1]);
            pw.y = cvtpk(p[h][2], p[h][3]);
            *(uint2*)&PTw[((((h << 1) + (quad >> 1)) * 16 + l15) << 3) + (quad & 1) * 4] = pw;
        }
        bfrag pA0 = *(const bfrag*)&PTw[lane * 8];
        bfrag pA1 = *(const bfrag*)&PTw[512 + lane * 8];

        #pragma unroll
        for (int c = 0; c < 4; ++c) {
            bfrag v0 = *(const bfrag*)(Vb + c * 2048 + c0);
            bfrag v1 = *(const bfrag*)(Vb + c * 2048 + c1);
            O[c] = MFMA16(pA0, v0, O[c]);
            O[c] = MFMA16(pA1, v1, O[c]);
        }

        __syncthreads();   // next tile landed (all waves); buf reusable
    }

    // ---- tail tile kt = ntiles-1: keys q0..q0+63, per-wave masking ----
    {
        const int buf = (ntiles - 1) & 1;
        const char* Kb = KtR + buf * 8192;
        const char* Vb = VsR + buf * 8192;

        float p[4][4];
        float mt = -INFINITY;
        #pragma unroll
        for (int h = 0; h < 4; ++h) {
            if (h <= w) {                       // wave-uniform branch
                bfrag a0 = *(const bfrag*)(Kb + h * 2048 + c0);
                bfrag a1 = *(const bfrag*)(Kb + h * 2048 + c1);
                f4 s = (f4){0.f, 0.f, 0.f, 0.f};
                s = MFMA16(a0, Qf0, s);
                s = MFMA16(a1, Qf1, s);
                if (h == w) {
                    #pragma unroll
                    for (int r = 0; r < 4; ++r) {
                        float v = (quad * 4 + r <= l15) ? s[r] : -INFINITY;
                        p[h][r] = v;
                        mt = fmaxf(mt, v);
                    }
                } else {
                    #pragma unroll
                    for (int r = 0; r < 4; ++r) {
                        p[h][r] = s[r];
                        mt = fmaxf(mt, s[r]);
                    }
                }
            } else {
                #pragma unroll
                for (int r = 0; r < 4; ++r) p[h][r] = -INFINITY;
            }
        }
        mt = fmaxf(mt, __shfl_xor(mt, 16, 64));
        mt = fmaxf(mt, __shfl_xor(mt, 32, 64));

        if (__any(mt > m_prev + 8.f)) {
            float m_new = fmaxf(m_prev, mt);
            float alpha = EXP2(m_prev - m_new);
            l_run *= alpha;
            #pragma unroll
            for (int r = 0; r < 4; ++r) {
                float ar = __shfl(alpha, (lane & 48) + quad * 4 + r, 64);
                #pragma unroll
                for (int c = 0; c < 4; ++c) O[c][r] *= ar;
            }
            m_prev = m_new;
        }

        float rsum = 0.f;
        #pragma unroll
        for (int h = 0; h < 4; ++h)
            #pragma unroll
            for (int r = 0; r < 4; ++r) {
                float e = EXP2(p[h][r] - m_prev);   // exp2(-inf)=0 for masked
                p[h][r] = e;
                rsum += e;
            }
        rsum += __shfl_xor(rsum, 16, 64);
        rsum += __shfl_xor(rsum, 32, 64);
        l_run += rsum;

        #pragma unroll
        for (int h = 0; h < 4; ++h) {
            uint2 pw;
            pw.x = cvtpk(p[h][0], p[h][1]);
            pw.y = cvtpk(p[h][2], p[h][3]);
            *(uint2*)&PTw[((((h << 1) + (quad >> 1)) * 16 + l15) << 3) + (quad & 1) * 4] = pw;
        }
        bfrag pA0 = *(const bfrag*)&PTw[lane * 8];
        #pragma unroll
        for (int c = 0; c < 4; ++c) {
            bfrag v0 = *(const bfrag*)(Vb + c * 2048 + c0);
            O[c] = MFMA16(pA0, v0, O[c]);
        }
        if (w >= 2) {                           // keys 32..63 only for waves 2,3
            bfrag pA1 = *(const bfrag*)&PTw[512 + lane * 8];
            #pragma unroll
            for (int c = 0; c < 4; ++c) {
                bfrag v1 = *(const bfrag*)(Vb + c * 2048 + c1);
                O[c] = MFMA16(pA1, v1, O[c]);
            }
        }
    }

    // epilogue: bf16 ctx [B,S,D]
    const int b = bh >> 4, h = bh & 15;
    #pragma unroll
    for (int r = 0; r < 4; ++r) {
        float inv_l = 1.0f / __shfl(l_run, (lane & 48) + quad * 4 + r, 64);
        size_t base = ((size_t)b * Sdim + qw + quad * 4 + r) * Ddim + h * HDdim + l15;
        #pragma unroll
        for (int c = 0; c < 4; ++c)
            ctx[base + c * 16] = f2bf(O[c][r] * inv_l);
    }
}

// ---------------- launch ----------------
extern "C" void kernel_launch(void* const* d_in, const int* in_sizes, int n_in,
                              void* d_out, int out_size, void* d_ws, size_t ws_size,
                              hipStream_t stream)
{
    const int NX = Mdim * Ddim;
    const int NW = Ddim * Ddim;
    int xi = 0, wi[4] = {1, 3, 5, 7}, bi[4] = {2, 4, 6, 8}, nw = 0, nb = 0;
    bool sized = true;
    for (int i = 0; i < 9; ++i) {
        if (in_sizes[i] == NX) xi = i;
        else if (in_sizes[i] == NW) { if (nw < 4) wi[nw++] = i; }
        else if (in_sizes[i] == Ddim) { if (nb < 4) bi[nb++] = i; }
        else sized = false;
    }
    int iWq, iWk, iWv, iWo, ibq, ibk, ibv, ibo;
    if (!sized || xi == 0) {
        xi = 0; iWq = 1; ibq = 2; iWk = 3; ibk = 4; iWv = 5; ibv = 6; iWo = 7; ibo = 8;
    } else {
        iWk = wi[0]; iWo = wi[1]; iWq = wi[2]; iWv = wi[3];
        ibk = bi[0]; ibo = bi[1]; ibq = bi[2]; ibv = bi[3];
    }

    const float* x  = (const float*)d_in[xi];
    const float* Wq = (const float*)d_in[iWq];
    const float* bq = (const float*)d_in[ibq];
    const float* Wk = (const float*)d_in[iWk];
    const float* bk = (const float*)d_in[ibk];
    const float* Wv = (const float*)d_in[iWv];
    const float* bv = (const float*)d_in[ibv];
    const float* Wo = (const float*)d_in[iWo];
    const float* bo = (const float*)d_in[ibo];
    float* out = (float*)d_out;

    const size_t elems = (size_t)Mdim * Ddim;
    const size_t welems = (size_t)Ddim * Ddim;
    ushort_t* Qb    = (ushort_t*)d_ws;
    ushort_t* Kb    = Qb + elems;
    ushort_t* Vtb   = Kb + elems;
    ushort_t* Cb    = Vtb + elems;
    ushort_t* xb    = Cb + elems;
    ushort_t* qkvT  = xb + elems;
    ushort_t* WoT   = qkvT + 3 * welems;

    dim3 blk(256);
    // fused prep: z<4 wtrans quadrants, z>=4 cast_x slices (8*256 = 2048 blk)
    prep<<<dim3(16, 16, 12), blk, 0, stream>>>(x, xb, Wq, Wk, Wv, Wo, qkvT, WoT);

    gemm_mfma<0><<<dim3(3 * Ddim / 128, Mdim / 128), blk, 0, stream>>>(
        xb, qkvT, bq, bk, bv, Qb, Kb, Vtb, nullptr);

    // blocks: idx = (31-qb)*32 + bh  (idx%8==bh%8 -> per-XCD K/V locality)
    flash_mfma<<<dim3(32 * NBH), blk, 0, stream>>>(Qb, Kb, Vtb, Cb);

    gemm_mfma<1><<<dim3(Ddim / 128, Mdim / 128), blk, 0, stream>>>(
        Cb, WoT, bo, nullptr, nullptr, nullptr, nullptr, nullptr, out);
}

// Round 10
// 182.597 us; speedup vs baseline: 1.0671x; 1.0575x over previous
//
#include <hip/hip_runtime.h>
#include <hip/hip_bf16.h>
#include <math.h>

// B=2, S=2048, D=1024, H=16, HD=64. Inputs fp32, output fp32.
// R18: R17's two gemm changes reverted (XCD swizzle thrashed L2: FETCH
// 36->54MB; batched barriers +VGPR). gemm0 = exact R15 serial (best).
// NEW: MODE1 (output proj) was 45.6us for 1/3 of gemm0's FLOPs — 256
// blocks = 1 block/CU = fully exposed K-step latency. Replaced with a
// 64x128-tile kernel: 512 blocks = 2/CU, wave = 32x64 (acc[2][4]),
// same proven serial fence shape. flash/prep byte-identical to R15.

#define Bdim  2
#define Sdim  2048
#define Ddim  1024
#define Hn    16
#define HDdim 64
#define Mdim  (Bdim * Sdim)   // 4096

// 0.125 (1/sqrt(64)) * log2(e): Q pre-scaled so QK^T is in log2 domain.
#define QSCALE 0.18033688011112042f

typedef unsigned short ushort_t;
typedef __attribute__((ext_vector_type(8))) short bfrag;   // 8 bf16 (4 VGPR)
typedef __attribute__((ext_vector_type(4))) float f4;

__device__ __forceinline__ ushort_t f2bf(float f) {
    union { float f; unsigned int i; } c;
    c.f = f;
    unsigned int x = c.i;
    unsigned int r = (x + 0x7fffu + ((x >> 16) & 1u)) >> 16;  // RNE
    return (ushort_t)r;
}

// packed bf16 convert: dst.lo = bf16(lo), dst.hi = bf16(hi)  [T12, m240]
__device__ __forceinline__ unsigned cvtpk(float lo, float hi) {
    unsigned r;
    asm("v_cvt_pk_bf16_f32 %0, %1, %2" : "=v"(r) : "v"(lo), "v"(hi));
    return r;
}

__device__ __forceinline__ void glds16(const void* g, void* l) {
    __builtin_amdgcn_global_load_lds(
        (const __attribute__((address_space(1))) unsigned int*)g,
        (__attribute__((address_space(3))) unsigned int*)l, 16, 0, 0);
}

// -------- prep: fused {cast x fp32->bf16} + {transpose-cast weights} -------
// grid (16,16,12): z<4 = wtrans quadrant z; z>=4 = cast_x slice (8x256 blk).
__global__ __launch_bounds__(256)
void prep(const float* __restrict__ x, ushort_t* __restrict__ xb,
          const float* __restrict__ W0, const float* __restrict__ W1,
          const float* __restrict__ W2, const float* __restrict__ W3,
          ushort_t* __restrict__ qkvT, ushort_t* __restrict__ oT)
{
    __shared__ ushort_t t[64][72];   // [n][k], padded (wtrans path only)
    const int tid = threadIdx.x;
    const int z = blockIdx.z;

    if (z >= 4) {
        // ---- cast_x: linear block over 2048 ----
        size_t blk = (size_t)(z - 4) * 256 + blockIdx.y * 16 + blockIdx.x;
        size_t i = (blk * 256 + tid) * 8;
        float4 a = *(const float4*)(x + i);
        float4 b = *(const float4*)(x + i + 4);
        ushort_t o[8] = {f2bf(a.x), f2bf(a.y), f2bf(a.z), f2bf(a.w),
                         f2bf(b.x), f2bf(b.y), f2bf(b.z), f2bf(b.w)};
        *(bfrag*)(xb + i) = *(const bfrag*)o;
        return;
    }

    // ---- wtrans: W[k][n] fp32 -> Wt[n][k] bf16 ----
    const float* W = (z == 0) ? W0 : (z == 1) ? W1 : (z == 2) ? W2 : W3;
    const int k0 = blockIdx.y * 64, n0 = blockIdx.x * 64;

    const int r = tid >> 4, c4 = (tid & 15) * 4;
    #pragma unroll
    for (int rr = 0; rr < 4; ++rr) {
        int k = r + rr * 16;
        float4 v = *(const float4*)&W[(size_t)(k0 + k) * Ddim + n0 + c4];
        t[c4 + 0][k] = f2bf(v.x);
        t[c4 + 1][k] = f2bf(v.y);
        t[c4 + 2][k] = f2bf(v.z);
        t[c4 + 3][k] = f2bf(v.w);
    }
    __syncthreads();
    ushort_t* out = (z < 3) ? (qkvT + (size_t)z * Ddim * Ddim) : oT;
    const int n = tid >> 2, kc = (tid & 3) * 16;
    *(bfrag*)&out[(size_t)(n0 + n) * Ddim + k0 + kc] = *(const bfrag*)&t[n][kc];
    *(bfrag*)&out[(size_t)(n0 + n) * Ddim + k0 + kc + 8] = *(const bfrag*)&t[n][kc + 8];
}

// ---------------- MFMA GEMM MODE0 (m97 structure, NT; R12 serial) ----------
// Ntot=3072 fused QKV; scatter bf16 to Q,K [B,H,S,HD], Vt [B,H,HD,S].
// Q is pre-scaled by QSCALE (softmax runs in exp2 domain).
__global__ __launch_bounds__(256)
void gemm_qkv(const ushort_t* __restrict__ A, const ushort_t* __restrict__ Bt,
              const float* __restrict__ bQ, const float* __restrict__ bK,
              const float* __restrict__ bV,
              ushort_t* __restrict__ oQ, ushort_t* __restrict__ oK,
              ushort_t* __restrict__ oVt)
{
    __shared__ ushort_t As[128 * 32];   // [row][k], 64 B rows
    __shared__ ushort_t Bs[128 * 32];

    const int tid  = threadIdx.x;
    const int lane = tid & 63;
    const int w    = tid >> 6;
    const int l15  = lane & 15;
    const int quad = lane >> 4;
    const int wr   = w >> 1, wc = w & 1;
    const int m0 = blockIdx.y * 128;
    const int n0 = blockIdx.x * 128;

    f4 acc[4][4];
    #pragma unroll
    for (int i = 0; i < 4; ++i)
        #pragma unroll
        for (int j = 0; j < 4; ++j) acc[i][j] = (f4){0.f, 0.f, 0.f, 0.f};

    const int srow  = w * 32 + (lane >> 2);
    const int selem = (lane & 3) * 8;
    const ushort_t* gA = A  + (size_t)(m0 + srow) * Ddim + selem;
    const ushort_t* gB = Bt + (size_t)(n0 + srow) * Ddim + selem;
    char* lA0 = (char*)As + (w * 32) * 64;
    char* lB0 = (char*)Bs + (w * 32) * 64;

    for (int kk = 0; kk < Ddim; kk += 32) {
        __syncthreads();
        glds16(gA + kk,              lA0);
        glds16(gA + 16 * Ddim + kk,  lA0 + 1024);
        glds16(gB + kk,              lB0);
        glds16(gB + 16 * Ddim + kk,  lB0 + 1024);
        __syncthreads();

        bfrag Af[4], Bf[4];
        #pragma unroll
        for (int i = 0; i < 4; ++i)
            Af[i] = *(const bfrag*)&As[(wr * 64 + i * 16 + l15) * 32 + quad * 8];
        #pragma unroll
        for (int j = 0; j < 4; ++j)
            Bf[j] = *(const bfrag*)&Bs[(wc * 64 + j * 16 + l15) * 32 + quad * 8];
        #pragma unroll
        for (int i = 0; i < 4; ++i)
            #pragma unroll
            for (int j = 0; j < 4; ++j)
                acc[i][j] = __builtin_amdgcn_mfma_f32_16x16x32_bf16(Af[i], Bf[j], acc[i][j], 0, 0, 0);
    }

    const int sel   = n0 >> 10;
    const int dbase = n0 & 1023;
    const float* bias = (sel == 0) ? bQ : (sel == 1) ? bK : bV;
    ushort_t* dst = (sel == 0) ? oQ : (sel == 1) ? oK : oVt;
    #pragma unroll
    for (int j = 0; j < 4; ++j) {
        int dn = dbase + wc * 64 + j * 16 + l15;
        float bv = bias[dn];
        int h = dn >> 6, e = dn & 63;
        if (sel < 2) {
            // Q/K: [B,H,S,HD] scatter, per-element (row stride 128B)
            #pragma unroll
            for (int i = 0; i < 4; ++i) {
                #pragma unroll
                for (int r = 0; r < 4; ++r) {
                    int m = m0 + wr * 64 + i * 16 + quad * 4 + r;
                    int b = m >> 11, s = m & 2047;
                    float v = acc[i][j][r] + bv;
                    if (sel == 0) v *= QSCALE;
                    dst[((((size_t)b * Hn + h) * Sdim + s) << 6) + e] = f2bf(v);
                }
            }
        } else {
            // Vt: [B,H,HD,S] — s consecutive across r -> paired stores
            #pragma unroll
            for (int i = 0; i < 4; ++i) {
                #pragma unroll
                for (int rp = 0; rp < 2; ++rp) {
                    int m = m0 + wr * 64 + i * 16 + quad * 4 + rp * 2;
                    int b = m >> 11, s = m & 2047;   // s even
                    unsigned pv = cvtpk(acc[i][j][rp * 2] + bv,
                                        acc[i][j][rp * 2 + 1] + bv);
                    *(unsigned*)&dst[(((size_t)b * Hn + h) * HDdim + e) * Sdim + s] = pv;
                }
            }
        }
    }
}

// ---------------- MFMA GEMM MODE1: output proj, 64x128 tile ---------------
// grid (8, 64) = 512 blocks = 2/CU (vs 1/CU at 128x128 -> latency exposed).
// Wave w owns rows wrow*32 (2 frags) x cols wcol*64 (4 frags), acc[2][4].
// Same serial fence shape and fragment-index pattern as gemm_qkv.
__global__ __launch_bounds__(256)
void gemm_on(const ushort_t* __restrict__ A, const ushort_t* __restrict__ Bt,
             const float* __restrict__ bo, float* __restrict__ oF)
{
    __shared__ ushort_t As[64 * 32];    // 4 KB, 64 B rows
    __shared__ ushort_t Bs[128 * 32];   // 8 KB

    const int tid  = threadIdx.x;
    const int lane = tid & 63;
    const int w    = tid >> 6;
    const int l15  = lane & 15;
    const int quad = lane >> 4;
    const int wrow = w >> 1, wcol = w & 1;
    const int m0 = blockIdx.y * 64;
    const int n0 = blockIdx.x * 128;

    f4 acc[2][4];
    #pragma unroll
    for (int i = 0; i < 2; ++i)
        #pragma unroll
        for (int j = 0; j < 4; ++j) acc[i][j] = (f4){0.f, 0.f, 0.f, 0.f};

    // staging: wave w covers 16 rows (lane>>2), 4x16B blocks per row
    const int srow  = w * 16 + (lane >> 2);      // 0..63
    const int selem = (lane & 3) * 8;
    const ushort_t* gA  = A  + (size_t)(m0 + srow) * Ddim + selem;
    const ushort_t* gB  = Bt + (size_t)(n0 + srow) * Ddim + selem;        // rows 0..63
    const ushort_t* gB2 = Bt + (size_t)(n0 + 64 + srow) * Ddim + selem;   // rows 64..127
    char* lA0 = (char*)As + w * 1024;
    char* lB0 = (char*)Bs + w * 1024;

    for (int kk = 0; kk < Ddim; kk += 32) {
        __syncthreads();
        glds16(gA + kk,  lA0);
        glds16(gB + kk,  lB0);
        glds16(gB2 + kk, lB0 + 4096);
        __syncthreads();

        bfrag Af[2], Bf[4];
        #pragma unroll
        for (int i = 0; i < 2; ++i)
            Af[i] = *(const bfrag*)&As[(wrow * 32 + i * 16 + l15) * 32 + quad * 8];
        #pragma unroll
        for (int j = 0; j < 4; ++j)
            Bf[j] = *(const bfrag*)&Bs[(wcol * 64 + j * 16 + l15) * 32 + quad * 8];
        #pragma unroll
        for (int i = 0; i < 2; ++i)
            #pragma unroll
            for (int j = 0; j < 4; ++j)
                acc[i][j] = __builtin_amdgcn_mfma_f32_16x16x32_bf16(Af[i], Bf[j], acc[i][j], 0, 0, 0);
    }

    #pragma unroll
    for (int j = 0; j < 4; ++j) {
        int n = n0 + wcol * 64 + j * 16 + l15;
        float bv = bo[n];
        #pragma unroll
        for (int i = 0; i < 2; ++i)
            #pragma unroll
            for (int r = 0; r < 4; ++r) {
                int m = m0 + wrow * 32 + i * 16 + quad * 4 + r;
                oF[(size_t)m * Ddim + n] = acc[i][j][r] + bv;
            }
    }
}

// ---------------- Flash attention: 4 waves / 64 q rows, async LDS dbuf -----
// (byte-identical to R15, which passed at 44.6us)
#define NBH (Bdim * Hn)       // 32

#define MFMA16(a, b, c) __builtin_amdgcn_mfma_f32_16x16x32_bf16(a, b, c, 0, 0, 0)
#define EXP2(x) __builtin_amdgcn_exp2f(x)

__global__ __launch_bounds__(256, 4)
void flash_mfma(const ushort_t* __restrict__ Q, const ushort_t* __restrict__ K,
                const ushort_t* __restrict__ Vt, ushort_t* __restrict__ ctx)
{
    __shared__ ushort_t KtS[2][64 * 64];   // [key][d], 16B blocks XOR-swizzled
    __shared__ ushort_t VsS[2][64 * 64];   // [d][key], same swizzle
    __shared__ ushort_t PTS[4][1024];      // per-wave P^T, fragment order

    const int tid  = threadIdx.x;
    const int lane = tid & 63;
    const int w    = tid >> 6;
    const int l15  = lane & 15;
    const int quad = lane >> 4;

    const int qb = 31 - (blockIdx.x >> 5);     // longest-first
    const int bh = blockIdx.x & 31;            // idx%8==bh%8 -> XCD affinity
    const int q0 = qb * 64;
    const int qw = q0 + w * 16;
    const int ntiles = qb + 1;                 // 64-key tiles (last is masked)

    const ushort_t* Qrow = Q + ((size_t)bh * Sdim + qw + l15) * HDdim;
    const bfrag Qf0 = *(const bfrag*)(Qrow + quad * 8);
    const bfrag Qf1 = *(const bfrag*)(Qrow + 32 + quad * 8);

    const ushort_t* Kp = K  + (size_t)bh * Sdim * HDdim;
    const ushort_t* Vp = Vt + (size_t)bh * HDdim * Sdim;

    // --- staging: pre-swizzled global source -> linear LDS dest ---
    const int srow = w * 8 + (lane >> 3);                    // 0..31 (+32 half 2)
    const int scol = ((lane & 7) ^ (lane >> 3)) * 8;         // swizzled elems
    const ushort_t* gK = Kp + (size_t)srow * HDdim + scol;
    const ushort_t* gV = Vp + (size_t)srow * Sdim + scol;
    char* ldsK = (char*)KtS + w * 1024;                      // wave-uniform
    char* ldsV = (char*)VsS + w * 1024;
    ushort_t* PTw = PTS[w];

    // --- fragment-read swizzled column offsets (row&7 == l15&7) ---
    const int sw = l15 & 7;
    const int c0 = (quad ^ sw) << 4;    // bytes, k-half 0
    const int c1 = c0 ^ 64;             // k-half 1 (block quad^4)
    const char* KtR = (const char*)KtS + l15 * 128;
    const char* VsR = (const char*)VsS + l15 * 128;

    f4 O[4];
    #pragma unroll
    for (int c = 0; c < 4; ++c) O[c] = (f4){0.f, 0.f, 0.f, 0.f};
    float m_prev = -INFINITY, l_run = 0.f;

    // prologue: stage tile 0 -> buf 0
    glds16(gK,                       ldsK);
    glds16(gK + 32 * HDdim,          ldsK + 4096);
    glds16(gV,                       ldsV);
    glds16(gV + (size_t)32 * Sdim,   ldsV + 4096);
    __syncthreads();

    for (int kt = 0; kt < ntiles - 1; ++kt) {
        const int k0  = kt << 6;
        const int buf = kt & 1;
        const int nb  = buf ^ 1;

        // STAGE next tile into other buffer; latency hidden by this tile's
        // compute; drained by the __syncthreads at the end of this iter.
        {
            const size_t kn = (size_t)(k0 + 64);
            glds16(gK + kn * HDdim,               ldsK + nb * 8192);
            glds16(gK + (kn + 32) * HDdim,        ldsK + nb * 8192 + 4096);
            glds16(gV + kn,                       ldsV + nb * 8192);
            glds16(gV + kn + (size_t)32 * Sdim,   ldsV + nb * 8192 + 4096);
        }

        const char* Kb = KtR + buf * 8192;
        const char* Vb = VsR + buf * 8192;

        // QK^T (log2 domain): p[h][r] = score(key k0+h*16+quad*4+r, q qw+l15)
        float p[4][4];
        #pragma unroll
        for (int h = 0; h < 4; ++h) {
            bfrag a0 = *(const bfrag*)(Kb + h * 2048 + c0);
            bfrag a1 = *(const bfrag*)(Kb + h * 2048 + c1);
            f4 s = (f4){0.f, 0.f, 0.f, 0.f};
            s = MFMA16(a0, Qf0, s);
            s = MFMA16(a1, Qf1, s);
            #pragma unroll
            for (int r = 0; r < 4; ++r) p[h][r] = s[r];
        }

        float mh0 = fmaxf(fmaxf(p[0][0], p[0][1]), fmaxf(p[0][2], p[0][3]));
        float mh1 = fmaxf(fmaxf(p[1][0], p[1][1]), fmaxf(p[1][2], p[1][3]));
        float mh2 = fmaxf(fmaxf(p[2][0], p[2][1]), fmaxf(p[2][2], p[2][3]));
        float mh3 = fmaxf(fmaxf(p[3][0], p[3][1]), fmaxf(p[3][2], p[3][3]));
        float mt = fmaxf(fmaxf(mh0, mh1), fmaxf(mh2, mh3));
        mt = fmaxf(mt, __shfl_xor(mt, 16, 64));
        mt = fmaxf(mt, __shfl_xor(mt, 32, 64));

        if (__any(mt > m_prev + 8.f)) {     // defer-max rescale
            float m_new = fmaxf(m_prev, mt);
            float alpha = EXP2(m_prev - m_new);
            l_run *= alpha;
            #pragma unroll
            for (int r = 0; r < 4; ++r) {
                float ar = __shfl(alpha, (lane & 48) + quad * 4 + r, 64);
                #pragma unroll
                for (int c = 0; c < 4; ++c) O[c][r] *= ar;
            }
            m_prev = m_new;
        }

        float rs0 = 0.f, rs1 = 0.f, rs2 = 0.f, rs3 = 0.f;
        #pragma unroll
        for (int r = 0; r < 4; ++r) {
            p[0][r] = EXP2(p[0][r] - m_prev); rs0 += p[0][r];
            p[1][r] = EXP2(p[1][r] - m_prev); rs1 += p[1][r];
            p[2][r] = EXP2(p[2][r] - m_prev); rs2 += p[2][r];
            p[3][r] = EXP2(p[3][r] - m_prev); rs3 += p[3][r];
        }
        float rsum = (rs0 + rs1) + (rs2 + rs3);
        rsum += __shfl_xor(rsum, 16, 64);
        rsum += __shfl_xor(rsum, 32, 64);
        l_run += rsum;

        // P^T -> per-wave LDS, fragment order [keyblk][q][8]; packed cvt_pk
        #pragma unroll
        for (int h = 0; h < 4; ++h) {
            uint2 pw;
            pw.x = cvtpk(p[h][0], p[h][1]);
            pw.y = cvtpk(p[h][2], p[h][3]);
            *(uint2*)&PTw[((((h << 1) + (quad >> 1)) * 16 + l15) << 3) + (quad & 1) * 4] = pw;
        }
        bfrag pA0 = *(const bfrag*)&PTw[lane * 8];
        bfrag pA1 = *(const bfrag*)&PTw[512 + lane * 8];

        #pragma unroll
        for (int c = 0; c < 4; ++c) {
            bfrag v0 = *(const bfrag*)(Vb + c * 2048 + c0);
            bfrag v1 = *(const bfrag*)(Vb + c * 2048 + c1);
            O[c] = MFMA16(pA0, v0, O[c]);
            O[c] = MFMA16(pA1, v1, O[c]);
        }

        __syncthreads();   // next tile landed (all waves); buf reusable
    }

    // ---- tail tile kt = ntiles-1: keys q0..q0+63, per-wave masking ----
    {
        const int buf = (ntiles - 1) & 1;
        const char* Kb = KtR + buf * 8192;
        const char* Vb = VsR + buf * 8192;

        float p[4][4];
        float mt = -INFINITY;
        #pragma unroll
        for (int h = 0; h < 4; ++h) {
            if (h <= w) {                       // wave-uniform branch
                bfrag a0 = *(const bfrag*)(Kb + h * 2048 + c0);
                bfrag a1 = *(const bfrag*)(Kb + h * 2048 + c1);
                f4 s = (f4){0.f, 0.f, 0.f, 0.f};
                s = MFMA16(a0, Qf0, s);
                s = MFMA16(a1, Qf1, s);
                if (h == w) {
                    #pragma unroll
                    for (int r = 0; r < 4; ++r) {
                        float v = (quad * 4 + r <= l15) ? s[r] : -INFINITY;
                        p[h][r] = v;
                        mt = fmaxf(mt, v);
                    }
                } else {
                    #pragma unroll
                    for (int r = 0; r < 4; ++r) {
                        p[h][r] = s[r];
                        mt = fmaxf(mt, s[r]);
                    }
                }
            } else {
                #pragma unroll
                for (int r = 0; r < 4; ++r) p[h][r] = -INFINITY;
            }
        }
        mt = fmaxf(mt, __shfl_xor(mt, 16, 64));
        mt = fmaxf(mt, __shfl_xor(mt, 32, 64));

        if (__any(mt > m_prev + 8.f)) {
            float m_new = fmaxf(m_prev, mt);
            float alpha = EXP2(m_prev - m_new);
            l_run *= alpha;
            #pragma unroll
            for (int r = 0; r < 4; ++r) {
                float ar = __shfl(alpha, (lane & 48) + quad * 4 + r, 64);
                #pragma unroll
                for (int c = 0; c < 4; ++c) O[c][r] *= ar;
            }
            m_prev = m_new;
        }

        float rsum = 0.f;
        #pragma unroll
        for (int h = 0; h < 4; ++h)
            #pragma unroll
            for (int r = 0; r < 4; ++r) {
                float e = EXP2(p[h][r] - m_prev);   // exp2(-inf)=0 for masked
                p[h][r] = e;
                rsum += e;
            }
        rsum += __shfl_xor(rsum, 16, 64);
        rsum += __shfl_xor(rsum, 32, 64);
        l_run += rsum;

        #pragma unroll
        for (int h = 0; h < 4; ++h) {
            uint2 pw;
            pw.x = cvtpk(p[h][0], p[h][1]);
            pw.y = cvtpk(p[h][2], p[h][3]);
            *(uint2*)&PTw[((((h << 1) + (quad >> 1)) * 16 + l15) << 3) + (quad & 1) * 4] = pw;
        }
        bfrag pA0 = *(const bfrag*)&PTw[lane * 8];
        #pragma unroll
        for (int c = 0; c < 4; ++c) {
            bfrag v0 = *(const bfrag*)(Vb + c * 2048 + c0);
            O[c] = MFMA16(pA0, v0, O[c]);
        }
        if (w >= 2) {                           // keys 32..63 only for waves 2,3
            bfrag pA1 = *(const bfrag*)&PTw[512 + lane * 8];
            #pragma unroll
            for (int c = 0; c < 4; ++c) {
                bfrag v1 = *(const bfrag*)(Vb + c * 2048 + c1);
                O[c] = MFMA16(pA1, v1, O[c]);
            }
        }
    }

    // epilogue: bf16 ctx [B,S,D]
    const int b = bh >> 4, h = bh & 15;
    #pragma unroll
    for (int r = 0; r < 4; ++r) {
        float inv_l = 1.0f / __shfl(l_run, (lane & 48) + quad * 4 + r, 64);
        size_t base = ((size_t)b * Sdim + qw + quad * 4 + r) * Ddim + h * HDdim + l15;
        #pragma unroll
        for (int c = 0; c < 4; ++c)
            ctx[base + c * 16] = f2bf(O[c][r] * inv_l);
    }
}

// ---------------- launch ----------------
extern "C" void kernel_launch(void* const* d_in, const int* in_sizes, int n_in,
                              void* d_out, int out_size, void* d_ws, size_t ws_size,
                              hipStream_t stream)
{
    const int NX = Mdim * Ddim;
    const int NW = Ddim * Ddim;
    int xi = 0, wi[4] = {1, 3, 5, 7}, bi[4] = {2, 4, 6, 8}, nw = 0, nb = 0;
    bool sized = true;
    for (int i = 0; i < 9; ++i) {
        if (in_sizes[i] == NX) xi = i;
        else if (in_sizes[i] == NW) { if (nw < 4) wi[nw++] = i; }
        else if (in_sizes[i] == Ddim) { if (nb < 4) bi[nb++] = i; }
        else sized = false;
    }
    int iWq, iWk, iWv, iWo, ibq, ibk, ibv, ibo;
    if (!sized || xi == 0) {
        xi = 0; iWq = 1; ibq = 2; iWk = 3; ibk = 4; iWv = 5; ibv = 6; iWo = 7; ibo = 8;
    } else {
        iWk = wi[0]; iWo = wi[1]; iWq = wi[2]; iWv = wi[3];
        ibk = bi[0]; ibo = bi[1]; ibq = bi[2]; ibv = bi[3];
    }

    const float* x  = (const float*)d_in[xi];
    const float* Wq = (const float*)d_in[iWq];
    const float* bq = (const float*)d_in[ibq];
    const float* Wk = (const float*)d_in[iWk];
    const float* bk = (const float*)d_in[ibk];
    const float* Wv = (const float*)d_in[iWv];
    const float* bv = (const float*)d_in[ibv];
    const float* Wo = (const float*)d_in[iWo];
    const float* bo = (const float*)d_in[ibo];
    float* out = (float*)d_out;

    const size_t elems = (size_t)Mdim * Ddim;
    const size_t welems = (size_t)Ddim * Ddim;
    ushort_t* Qb    = (ushort_t*)d_ws;
    ushort_t* Kb    = Qb + elems;
    ushort_t* Vtb   = Kb + elems;
    ushort_t* Cb    = Vtb + elems;
    ushort_t* xb    = Cb + elems;
    ushort_t* qkvT  = xb + elems;
    ushort_t* WoT   = qkvT + 3 * welems;

    dim3 blk(256);
    // fused prep: z<4 wtrans quadrants, z>=4 cast_x slices (8*256 = 2048 blk)
    prep<<<dim3(16, 16, 12), blk, 0, stream>>>(x, xb, Wq, Wk, Wv, Wo, qkvT, WoT);

    gemm_qkv<<<dim3(3 * Ddim / 128, Mdim / 128), blk, 0, stream>>>(
        xb, qkvT, bq, bk, bv, Qb, Kb, Vtb);

    // blocks: idx = (31-qb)*32 + bh  (idx%8==bh%8 -> per-XCD K/V locality)
    flash_mfma<<<dim3(32 * NBH), blk, 0, stream>>>(Qb, Kb, Vtb, Cb);

    // output proj: 64x128 tiles -> 512 blocks = 2/CU
    gemm_on<<<dim3(Ddim / 128, Mdim / 64), blk, 0, stream>>>(Cb, WoT, bo, out);
}